// Round 3
// baseline (188.691 us; speedup 1.0000x reference)
//
#include <hip/hip_runtime.h>

// OpeningLoss2D: grey opening, flat 2x2 SE (scipy size=2, 'reflect' == edge
// clamp for pad 1), then mean((x - opening(x))^2) over [8,16,512,512] fp32.
//
//   h[a][j]  = min(x[a][j-1], x[a][j])           (col clamp at 0)
//   er[a]    = min(h[a-1], h[a])                 (row clamp at 0)
//   g[a][j]  = max(er[a][j], er[a][j+1])         (col clamp at 511)
//   smooth[i]= max(g[i], g[i+1])                 (row clamp at 511)
//
// Row-streaming strips: one wave = full 512-col row (8 cols/lane), sweeps
// R=32 output rows keeping h/g/x of the previous row in registers. Each
// input row loaded once per strip (34/32 = 1.0625x fetch). 2-row-deep
// rotating prefetch keeps ~4 KB/wave in flight (8 waves/CU -> 32 KB/CU,
// above the ~9.2 KB needed to cover ~900cy HBM latency at 10.25 B/cy/CU).
// Horizontal neighbors via __shfl (no extra VMEM).

#define BLK 256
#define R_STRIP 32
#define GRID 512   // 2048 strips, 4 waves/block, 1 strip/wave

__device__ __forceinline__ void compute_h(float4 u0, float4 u1, int lane,
                                          float h[9]) {
    float xl = __shfl_up(u1.w, 1, 64);    // lane-1's col c0-1
    float xr = __shfl_down(u0.x, 1, 64);  // lane+1's col c0+8
    if (lane == 0)  xl = u0.x;            // col 0: h = x[0]
    if (lane == 63) xr = u1.w;            // col 512 -> clamp (value unused at 511)
    h[0] = fminf(xl, u0.x);
    h[1] = fminf(u0.x, u0.y);
    h[2] = fminf(u0.y, u0.z);
    h[3] = fminf(u0.z, u0.w);
    h[4] = fminf(u0.w, u1.x);
    h[5] = fminf(u1.x, u1.y);
    h[6] = fminf(u1.y, u1.z);
    h[7] = fminf(u1.z, u1.w);
    h[8] = fminf(u1.w, xr);
}

__global__ __launch_bounds__(BLK) void opening_strip_kernel(
    const float* __restrict__ x, float* __restrict__ partial, int nStrips)
{
    const int lane = threadIdx.x & 63;
    const int waveId = blockIdx.x * (BLK / 64) + (threadIdx.x >> 6);
    const int totalWaves = gridDim.x * (BLK / 64);
    float acc = 0.f;

    for (int strip = waveId; strip < nStrips; strip += totalWaves) {
        const int plane = strip >> 4;               // 512/R_STRIP = 16 strips/plane
        const int rs = (strip & 15) * R_STRIP;
        const int re = rs + R_STRIP - 1;            // <= 511
        const int aEnd = (re < 511) ? re + 1 : 511;
        const float* pl = x + (((long long)plane) << 18) + (lane << 3);

        float hp[9], gp[8], xk[8];

        // prologue: h for row max(rs-1, 0)
        {
            const int a0 = (rs > 0) ? rs - 1 : 0;
            const float* rp = pl + ((long long)a0 << 9);
            float4 u0 = *(const float4*)(rp);
            float4 u1 = *(const float4*)(rp + 4);
            compute_h(u0, u1, lane, hp);
        }
        // 2-deep rotating prefetch: p0 = row a, p1 = row a+1
        float4 p00, p01, p10, p11;
        {
            const float* rp = pl + ((long long)rs << 9);
            p00 = *(const float4*)(rp);
            p01 = *(const float4*)(rp + 4);
            p10 = *(const float4*)(rp + 512);     // rs+1 <= aEnd always (R=32)
            p11 = *(const float4*)(rp + 516);
        }

        for (int a = rs; a <= aEnd; ++a) {
            const float4 u0 = p00, u1 = p01;
            p00 = p10; p01 = p11;
            if (a + 2 <= aEnd) {                     // prefetch row a+2
                const float* np = pl + ((long long)(a + 2) << 9);
                p10 = *(const float4*)(np);
                p11 = *(const float4*)(np + 4);
            }
            float hc[9], er[9], gc[8];
            compute_h(u0, u1, lane, hc);
            #pragma unroll
            for (int c = 0; c < 9; ++c) er[c] = fminf(hp[c], hc[c]);
            if (lane == 63) er[8] = er[7];           // col-511 clamp for g
            #pragma unroll
            for (int c = 0; c < 8; ++c) gc[c] = fmaxf(er[c], er[c + 1]);

            if (a > rs) {                            // emit output row a-1
                #pragma unroll
                for (int k = 0; k < 8; ++k) {
                    const float d = xk[k] - fmaxf(gp[k], gc[k]);
                    acc = fmaf(d, d, acc);
                }
            }
            #pragma unroll
            for (int c = 0; c < 9; ++c) hp[c] = hc[c];
            #pragma unroll
            for (int c = 0; c < 8; ++c) gp[c] = gc[c];
            xk[0] = u0.x; xk[1] = u0.y; xk[2] = u0.z; xk[3] = u0.w;
            xk[4] = u1.x; xk[5] = u1.y; xk[6] = u1.z; xk[7] = u1.w;
        }
        if (re == 511) {                             // row 511: smooth = g[511]
            #pragma unroll
            for (int k = 0; k < 8; ++k) {
                const float d = xk[k] - gp[k];
                acc = fmaf(d, d, acc);
            }
        }
    }

    // wave shuffle reduce, then LDS across 4 waves, one partial per block
    #pragma unroll
    for (int off = 32; off > 0; off >>= 1)
        acc += __shfl_down(acc, off, 64);
    __shared__ float s[BLK / 64];
    if ((threadIdx.x & 63) == 0) s[threadIdx.x >> 6] = acc;
    __syncthreads();
    if (threadIdx.x == 0) {
        float t = 0.f;
        #pragma unroll
        for (int w = 0; w < BLK / 64; ++w) t += s[w];
        partial[blockIdx.x] = t;
    }
}

__global__ __launch_bounds__(256) void final_reduce_kernel(
    const float* __restrict__ partial, float* __restrict__ out, int n, float invN)
{
    float acc = 0.f;
    for (int idx = threadIdx.x; idx < n; idx += blockDim.x) acc += partial[idx];
    #pragma unroll
    for (int off = 32; off > 0; off >>= 1)
        acc += __shfl_down(acc, off, 64);
    __shared__ float s[4];
    if ((threadIdx.x & 63) == 0) s[threadIdx.x >> 6] = acc;
    __syncthreads();
    if (threadIdx.x == 0)
        out[0] = (s[0] + s[1] + s[2] + s[3]) * invN;
}

extern "C" void kernel_launch(void* const* d_in, const int* in_sizes, int n_in,
                              void* d_out, int out_size, void* d_ws, size_t ws_size,
                              hipStream_t stream) {
    const float* x = (const float*)d_in[0];
    float* out = (float*)d_out;
    float* ws = (float*)d_ws;                  // GRID floats of scratch
    const int N = in_sizes[0];                 // 8*16*512*512
    const int nStrips = (N >> 18) << 4;        // planes * 16

    opening_strip_kernel<<<GRID, BLK, 0, stream>>>(x, ws, nStrips);
    final_reduce_kernel<<<1, 256, 0, stream>>>(ws, out, GRID, 1.0f / (float)N);
}